// Round 9
// baseline (620.057 us; speedup 1.0000x reference)
//
#include <hip/hip_runtime.h>
#include <hip/hip_cooperative_groups.h>
#include <cstdint>
#include <cstddef>

namespace cg = cooperative_groups;

// ONLSTM cell: B=4096, D=1024, U=1024.
// pre16 = fp16([X|H] @ [[W_all],[U_all]] + b_all), single-fp16 MFMA.
// R1-R6: absmax (0.25) from fp32 softmax/cumsum path; threshold 1.55.
// GEMM: R9 ring config (best, ~110us) kept verbatim.
// R13/R14: tail re-chunk + fast transcendentals changed NOTHING — tail
// (total-gemm) is ~200us across R9/R10/R11/R14 regardless of tail code,
// vs ~70us ideal traffic. Hypothesis: per-kernel fixed cost x5 + p round-trip.
// R15 (this round): fuse softmax+scan+final into ONE cooperative kernel
// (512 blocks x 256 thr = 2/CU, 48KB LDS -> 3/CU capacity, co-residency ok):
//   Phase1: 8-row softmax for zft+zit, p kept in LDS (32KB; saves 16MB write
//           + 16MB re-read of pre16), part4 column-partials out.
//   fence + grid.sync + fence  (agent fences: L2 wb/inv for cross-XCD vis).
//   Phase2: block g scans its 512 chunk-partials -> off4.
//   fence + grid.sync + fence.
//   Phase3: gates from pre16, p from own LDS (persists across grid.sync),
//           cprev, fast transcendentals, write out.
// Removes 2 launches + ~65MB traffic. Numerics: p fp16-rounded identically;
// scan reassociation ~1e-7. absmax expected 0.25.

typedef _Float16 half8  __attribute__((ext_vector_type(8)));
typedef _Float16 half4v __attribute__((ext_vector_type(4)));
typedef float f32x4 __attribute__((ext_vector_type(4)));

__device__ __forceinline__ void async16(const _Float16* g, _Float16* l) {
  __builtin_amdgcn_global_load_lds(
      (const __attribute__((address_space(1))) void*)g,
      (__attribute__((address_space(3))) void*)l, 16, 0, 0);
}

struct Ptrs12 { const float* p[12]; };
struct Ptrs6  { const float* p[6];  };

// ---------------------------------------------------------------------------
// Merged prep: convert A (X|H -> fp16), convert+transpose B (x64 scale, fp16),
// build bias. Branch is block-uniform. (unchanged)
__global__ void prep(const float* __restrict__ X, const float* __restrict__ H,
                     Ptrs12 w, Ptrs6 bs,
                     _Float16* __restrict__ Ahi, _Float16* __restrict__ Bhi,
                     float* __restrict__ b_all) {
  __shared__ float tile[64][65];
  const int blk = blockIdx.x;
  const int t = threadIdx.x;
  if (blk < 8192) {
    size_t base = ((size_t)blk * 256 + t) * 4;
    int k = (int)(base & 2047);
    size_t b = base >> 11;
    const float* src = (k < 1024) ? (X + b * 1024 + k) : (H + b * 1024 + (k - 1024));
    float4 v = *(const float4*)src;
    half4v hi = { (_Float16)v.x, (_Float16)v.y, (_Float16)v.z, (_Float16)v.w };
    *(half4v*)(Ahi + base) = hi;
  } else if (blk < 11264) {
    int bb = blk - 8192;
    int mat = bb >> 8;
    int tl = bb & 255;
    int tr = tl >> 4, tc = tl & 15;
    int g = mat >> 1, s = mat & 1;
    const float* src = w.p[mat];
    int col = t & 63, r0 = t >> 6;
#pragma unroll
    for (int i = 0; i < 16; i++) {
      int row = i * 4 + r0;
      tile[row][col] = src[(size_t)(tr * 64 + row) * 1024 + tc * 64 + col];
    }
    __syncthreads();
    int c2 = t >> 2, kseg = t & 3;
    half8 v0, v1;
#pragma unroll
    for (int j = 0; j < 8; j++) {
      v0[j] = (_Float16)(tile[kseg * 16 + j][c2] * 64.0f);
      v1[j] = (_Float16)(tile[kseg * 16 + 8 + j][c2] * 64.0f);
    }
    size_t n  = (size_t)g * 1024 + tc * 64 + c2;
    size_t kk = (size_t)s * 1024 + tr * 64 + kseg * 16;
    *(half8*)(Bhi + n * 2048 + kk) = v0;
    *(half8*)(Bhi + n * 2048 + kk + 8) = v1;
  } else {
    int n = (blk - 11264) * 256 + t;
    b_all[n] = bs.p[n >> 10][n & 1023];
  }
}

// ---------------------------------------------------------------------------
// GEMM: A[4096,2048] @ Bt[6144,2048]^T / 64 + bias -> pre16 (fp16, row-major).
// R9 config verbatim (measured ~110us): triple-buffer ring BK=64, 1 barrier/
// tile, ks-split MFMA clusters, 3-bit XOR slot swizzle, grid 768 = 3 rounds.

#define LGKM0 asm volatile("s_waitcnt lgkmcnt(0)" ::: "memory")

__device__ __forceinline__ void wg_barrier() {
  __builtin_amdgcn_s_barrier();
  asm volatile("" ::: "memory");
}

__global__ __launch_bounds__(512, 2) void gemm_ring(
    const _Float16* __restrict__ Ah, const _Float16* __restrict__ Bh,
    const float* __restrict__ b_all, _Float16* __restrict__ pre16) {
  __shared__ __attribute__((aligned(16))) _Float16 lds[73728];

  const int bid = blockIdx.x;
  const int swz = (bid & 7) * 96 + (bid >> 3);
  const int nTile = swz / 32;
  const int mTile = swz % 32;

  const int t = threadIdx.x;
  const int lane = t & 63;
  const int wave = t >> 6;
  const int wm = wave >> 2, wn = wave & 3;
  const int kgrp = lane >> 4, frow = lane & 15;

  const _Float16* Abase = Ah + (size_t)mTile * 128 * 2048;
  const _Float16* Bbase = Bh + (size_t)nTile * 256 * 2048;

  f32x4 acc[4][4] = {};

  auto stage_tile = [&](int kt, int base) {
#pragma unroll
    for (int q = 0; q < 2; q++) {
      int s = q * 512 + t;
      int r = s >> 3, k8 = s & 7;
      int xs = k8 ^ (r & 7);
      async16(Abase + (size_t)r * 2048 + kt * 64 + xs * 8, lds + base + s * 8);
    }
#pragma unroll
    for (int q = 0; q < 4; q++) {
      int s = q * 512 + t;
      int r = s >> 3, k8 = s & 7;
      int xs = k8 ^ (r & 7);
      async16(Bbase + (size_t)r * 2048 + kt * 64 + xs * 8,
              lds + base + 8192 + s * 8);
    }
  };

  int cur = 0, nxt = 24576, nn = 49152;

  stage_tile(0, cur);
  stage_tile(1, nxt);
  asm volatile("s_waitcnt vmcnt(6)" ::: "memory");
  wg_barrier();

  for (int T = 0; T < 32; T++) {
    const _Float16* A_ = lds + cur;
    const _Float16* B_ = lds + cur + 8192;
    half8 af[4][2], bf[4][2];
#pragma unroll
    for (int mi = 0; mi < 4; mi++) {
      int r = wm * 64 + mi * 16 + frow;
#pragma unroll
      for (int ks = 0; ks < 2; ks++)
        af[mi][ks] = *(const half8*)(A_ + r * 64 +
                                     (((ks * 4 + kgrp) ^ (r & 7)) * 8));
    }
#pragma unroll
    for (int nj = 0; nj < 4; nj++) {
      int r = wn * 64 + nj * 16 + frow;
#pragma unroll
      for (int ks = 0; ks < 2; ks++)
        bf[nj][ks] = *(const half8*)(B_ + r * 64 +
                                     (((ks * 4 + kgrp) ^ (r & 7)) * 8));
    }
    if (T + 2 < 32) stage_tile(T + 2, nn);

    __builtin_amdgcn_s_setprio(1);
#pragma unroll
    for (int mi = 0; mi < 4; mi++)
#pragma unroll
      for (int nj = 0; nj < 4; nj++)
        acc[mi][nj] = __builtin_amdgcn_mfma_f32_16x16x32_f16(
            af[mi][0], bf[nj][0], acc[mi][nj], 0, 0, 0);
    __builtin_amdgcn_s_setprio(0);

    LGKM0;
    if (T < 30) {
      asm volatile("s_waitcnt vmcnt(6)" ::: "memory");
      wg_barrier();
    } else if (T == 30) {
      asm volatile("s_waitcnt vmcnt(0)" ::: "memory");
      wg_barrier();
    }

    __builtin_amdgcn_s_setprio(1);
#pragma unroll
    for (int mi = 0; mi < 4; mi++)
#pragma unroll
      for (int nj = 0; nj < 4; nj++)
        acc[mi][nj] = __builtin_amdgcn_mfma_f32_16x16x32_f16(
            af[mi][1], bf[nj][1], acc[mi][nj], 0, 0, 0);
    __builtin_amdgcn_s_setprio(0);

    int tmp = cur; cur = nxt; nxt = nn; nn = tmp;
  }

  __syncthreads();
  const float inv64 = 1.0f / 64.0f;
  const int cb = nTile * 256;
  float bias[4];
#pragma unroll
  for (int nj = 0; nj < 4; nj++)
    bias[nj] = b_all[cb + wn * 64 + nj * 16 + frow];
#pragma unroll
  for (int mi = 0; mi < 4; mi++) {
#pragma unroll
    for (int nj = 0; nj < 4; nj++) {
      int row = wm * 64 + mi * 16 + kgrp * 4;
      int col = wn * 64 + nj * 16 + frow;
#pragma unroll
      for (int j = 0; j < 4; j++)
        lds[(row + j) * 264 + col] =
            (_Float16)(acc[mi][nj][j] * inv64 + bias[nj]);
    }
  }
  __syncthreads();
#pragma unroll
  for (int rr = 0; rr < 8; rr++) {
    int L = rr * 4096 + t * 8;
    int row = L >> 8, col = L & 255;
    half8 v = *(const half8*)(lds + row * 264 + col);
    *(half8*)(pre16 + (size_t)(mTile * 128 + row) * 6144 + cb + col) = v;
  }
}

// ---------------------------------------------------------------------------
// Fused tail (cooperative): softmax(zft,zit) -> p in LDS + part4; grid sync;
// chunk scan -> off4; grid sync; gates+cumsum+cell/hidden -> out.
// Grid 512 x 256 (block ch = rows ch*8..ch*8+7); LDS 48KB -> 3 blocks/CU
// capacity >= 2 needed for co-residency. All phases fully uniform (no early
// returns) so every thread reaches both grid syncs.

__device__ __forceinline__ float fast_sigmoid(float x) {
  return __builtin_amdgcn_rcpf(1.f + __expf(-x));
}
__device__ __forceinline__ float fast_tanh(float x) {
  float xc = fminf(fmaxf(x, -15.f), 15.f);
  float e = __expf(2.f * xc);
  return (e - 1.f) * __builtin_amdgcn_rcpf(e + 1.f);
}

__global__ __launch_bounds__(256) void fused_tail(
    const _Float16* __restrict__ pre16, const float* __restrict__ cprev,
    f32x4* __restrict__ part4, f32x4* __restrict__ off4,
    float* __restrict__ out) {
  __shared__ _Float16 p_lds[8 * 2048];   // 32KB: [row][m*1024+col]
  __shared__ float wsum[4][1024];        // 16KB
  __shared__ f32x4 wtot[4];              // 64B (phase-2 cross-wave)

  cg::grid_group grid = cg::this_grid();

  const int ch = blockIdx.x;             // 0..511 (chunk of 8 rows)
  const int t = threadIdx.x;
  const int wave = t >> 6, lane = t & 63;

  // ---- Phase 1: softmax over zft (m=0) and zit (m=1); p -> LDS; partials.
#pragma unroll
  for (int m = 0; m < 2; m++) {
    f32x4 colacc[4] = {};
#pragma unroll
    for (int rr = 0; rr < 2; rr++) {
      int rloc = wave * 2 + rr;
      int b = ch * 8 + rloc;
      const _Float16* row = pre16 + (size_t)b * 6144 + (4 + m) * 1024;
      f32x4 v[4];
      float mx = -3.4e38f;
#pragma unroll
      for (int j = 0; j < 4; j++) {
        half4v h = *(const half4v*)(row + lane * 4 + 256 * j);
        v[j] = f32x4{ (float)h[0], (float)h[1], (float)h[2], (float)h[3] };
        mx = fmaxf(mx, fmaxf(fmaxf(v[j][0], v[j][1]), fmaxf(v[j][2], v[j][3])));
      }
#pragma unroll
      for (int off = 32; off > 0; off >>= 1) mx = fmaxf(mx, __shfl_xor(mx, off, 64));
      float sum = 0.f;
#pragma unroll
      for (int j = 0; j < 4; j++)
#pragma unroll
        for (int q = 0; q < 4; q++) { v[j][q] = __expf(v[j][q] - mx); sum += v[j][q]; }
#pragma unroll
      for (int off = 32; off > 0; off >>= 1) sum += __shfl_xor(sum, off, 64);
      float inv = 1.f / sum;
#pragma unroll
      for (int j = 0; j < 4; j++) {
        v[j] *= inv;
        half4v h = { (_Float16)v[j][0], (_Float16)v[j][1],
                     (_Float16)v[j][2], (_Float16)v[j][3] };
        *(half4v*)(&p_lds[rloc * 2048 + m * 1024 + lane * 4 + 256 * j]) = h;
        colacc[j] += v[j];
      }
    }
#pragma unroll
    for (int j = 0; j < 4; j++)
      *(f32x4*)(&wsum[wave][lane * 4 + 256 * j]) = colacc[j];
    __syncthreads();
    f32x4 s = *(const f32x4*)(&wsum[0][t * 4]);
    s += *(const f32x4*)(&wsum[1][t * 4]);
    s += *(const f32x4*)(&wsum[2][t * 4]);
    s += *(const f32x4*)(&wsum[3][t * 4]);
    part4[((size_t)m * 256 + t) * 512 + ch] = s;
    __syncthreads();
  }

  __threadfence();     // release: L2 writeback (cross-XCD visibility of part4)
  grid.sync();
  __threadfence();     // acquire: L2 invalidate before reading others' part4

  // ---- Phase 2: exclusive scan of 512 chunk-partials for group g = blockIdx.
  {
    const int g = ch;                     // 0..511 == m*256 + c4
    f32x4 e0 = part4[(size_t)g * 512 + 2 * t];
    f32x4 e1 = part4[(size_t)g * 512 + 2 * t + 1];
    f32x4 ps = e0 + e1;
    f32x4 incl = ps;
#pragma unroll
    for (int off = 1; off < 64; off <<= 1) {
      f32x4 o;
#pragma unroll
      for (int q = 0; q < 4; q++) o[q] = __shfl_up(incl[q], off, 64);
      if (lane >= off) incl += o;
    }
    if (lane == 63) wtot[wave] = incl;
    __syncthreads();
    f32x4 woff = {};
#pragma unroll
    for (int w = 0; w < 4; w++)
      if (w < wave) woff += wtot[w];
    f32x4 excl = woff + incl - ps;
    off4[(size_t)g * 512 + 2 * t] = excl;
    off4[(size_t)g * 512 + 2 * t + 1] = excl + e0;
  }

  __threadfence();
  grid.sync();
  __threadfence();

  // ---- Phase 3: gates + cumsum + cell/hidden for this block's 8 rows.
  {
    const int c4 = t, c = t * 4;
    f32x4 runf = off4[(size_t)c4 * 512 + ch];
    f32x4 runi = off4[(size_t)(256 + c4) * 512 + ch];
    for (int r = 0; r < 8; r++) {
      int b = ch * 8 + r;
      const _Float16* row = pre16 + (size_t)b * 6144;
      half4v zf = *(const half4v*)(row + c);
      half4v zi = *(const half4v*)(row + 1024 + c);
      half4v zo = *(const half4v*)(row + 2048 + c);
      half4v zc = *(const half4v*)(row + 3072 + c);
      half4v pf = *(const half4v*)(&p_lds[r * 2048 + c]);
      half4v pi = *(const half4v*)(&p_lds[r * 2048 + 1024 + c]);
      f32x4 cp = *(const f32x4*)(cprev + (size_t)b * 1024 + c);
      f32x4 hid, cel;
#pragma unroll
      for (int q = 0; q < 4; q++) {
        runf[q] += (float)pf[q];
        runi[q] += (float)pi[q];
        float ft = runf[q], it = 1.f - runi[q];
        float f  = fast_sigmoid((float)zf[q]);
        float ii = fast_sigmoid((float)zi[q]);
        float o  = fast_sigmoid((float)zo[q]);
        float chat = fast_tanh((float)zc[q]);
        float omega = ft * it;
        float fhat = f * omega + (ft - omega);
        float ihat = ii * omega + (it - omega);
        float cell = fhat * cp[q] + ihat * chat;
        hid[q] = o * fast_tanh(cell);
        cel[q] = cell;
      }
      *(f32x4*)(out + (size_t)b * 1024 + c) = hid;
      *(f32x4*)(out + (size_t)4194304 + (size_t)b * 1024 + c) = cel;
    }
  }
}

// ---------------------------------------------------------------------------
extern "C" void kernel_launch(void* const* d_in, const int* in_sizes, int n_in,
                              void* d_out, int out_size, void* d_ws, size_t ws_size,
                              hipStream_t stream) {
  const float* X = (const float*)d_in[0];
  const float* H = (const float*)d_in[1];
  const float* C = (const float*)d_in[2];

  char* ws = (char*)d_ws;
  _Float16* pre16 = (_Float16*)(ws);                      // 48 MB [4096][6144]
  _Float16* Ahi   = (_Float16*)(ws + 50331648);           // 16 MB (dead after gemm)
  _Float16* Bhi   = (_Float16*)(ws + 67108864);           // 24 MB (dead after gemm)
  float*    b_all = (float*)(ws + 92274688);              // 24 KB
  // part4/off4 (4 MB each) overlay the dead 16 MB Ahi region
  // [50331648, 67108864): gemm completes before fused_tail launches.
  f32x4*    part4 = (f32x4*)(ws + 50331648);              //  4 MB [2][256][512]x16B
  f32x4*    off4  = (f32x4*)(ws + 54525952);              //  4 MB

  Ptrs12 w;
  for (int g = 0; g < 6; g++) {
    w.p[2 * g]     = (const float*)d_in[3 + 3 * g];   // Wg
    w.p[2 * g + 1] = (const float*)d_in[4 + 3 * g];   // Ug
  }
  Ptrs6 bs;
  for (int g = 0; g < 6; g++) bs.p[g] = (const float*)d_in[5 + 3 * g];

  prep<<<11288, 256, 0, stream>>>(X, H, w, bs, Ahi, Bhi, b_all);
  gemm_ring<<<768, 512, 0, stream>>>(Ahi, Bhi, b_all, pre16);

  const _Float16* pre16c = pre16;
  float* outp = (float*)d_out;
  void* args[5] = { (void*)&pre16c, (void*)&C, (void*)&part4,
                    (void*)&off4, (void*)&outp };
  hipLaunchCooperativeKernel((const void*)fused_tail, dim3(512), dim3(256),
                             args, 0, stream);
}

// Round 10
// 302.883 us; speedup vs baseline: 2.0472x; 2.0472x over previous
//
#include <hip/hip_runtime.h>
#include <cstdint>
#include <cstddef>

// ONLSTM cell: B=4096, D=1024, U=1024.
// pre16 = fp16([X|H] @ [[W_all],[U_all]] + b_all), single-fp16 MFMA.
// R1-R6: absmax (0.25) from fp32 softmax/cumsum path; threshold 1.55.
// GEMM: 5 schedules (R8-R12) all 109-123us @ MfmaUtil 37-42%; R9 ring best.
// Tail: R13/R14 rewrites + R15 cooperative fusion all null-or-worse
//   (grid.sync = ~130us EACH on 8 non-coherent XCDs — R15 tail alone 311us).
//   Tail-internal structure is inside a +/-20us noise band; best measured
//   tail = R12's (8-row chunks, fast transcendentals): 181us.
// R16 (this round): banking round — best measured components, run together:
//   R9 gemm_ring verbatim (109-112us) + R12 tail verbatim + workspace overlay.

typedef _Float16 half8  __attribute__((ext_vector_type(8)));
typedef _Float16 half4v __attribute__((ext_vector_type(4)));
typedef float f32x4 __attribute__((ext_vector_type(4)));

__device__ __forceinline__ void async16(const _Float16* g, _Float16* l) {
  __builtin_amdgcn_global_load_lds(
      (const __attribute__((address_space(1))) void*)g,
      (__attribute__((address_space(3))) void*)l, 16, 0, 0);
}

struct Ptrs12 { const float* p[12]; };
struct Ptrs6  { const float* p[6];  };

// ---------------------------------------------------------------------------
// Merged prep: convert A (X|H -> fp16), convert+transpose B (x64 scale, fp16),
// build bias. Branch is block-uniform. (unchanged)
__global__ void prep(const float* __restrict__ X, const float* __restrict__ H,
                     Ptrs12 w, Ptrs6 bs,
                     _Float16* __restrict__ Ahi, _Float16* __restrict__ Bhi,
                     float* __restrict__ b_all) {
  __shared__ float tile[64][65];
  const int blk = blockIdx.x;
  const int t = threadIdx.x;
  if (blk < 8192) {
    size_t base = ((size_t)blk * 256 + t) * 4;
    int k = (int)(base & 2047);
    size_t b = base >> 11;
    const float* src = (k < 1024) ? (X + b * 1024 + k) : (H + b * 1024 + (k - 1024));
    float4 v = *(const float4*)src;
    half4v hi = { (_Float16)v.x, (_Float16)v.y, (_Float16)v.z, (_Float16)v.w };
    *(half4v*)(Ahi + base) = hi;
  } else if (blk < 11264) {
    int bb = blk - 8192;
    int mat = bb >> 8;
    int tl = bb & 255;
    int tr = tl >> 4, tc = tl & 15;
    int g = mat >> 1, s = mat & 1;
    const float* src = w.p[mat];
    int col = t & 63, r0 = t >> 6;
#pragma unroll
    for (int i = 0; i < 16; i++) {
      int row = i * 4 + r0;
      tile[row][col] = src[(size_t)(tr * 64 + row) * 1024 + tc * 64 + col];
    }
    __syncthreads();
    int c2 = t >> 2, kseg = t & 3;
    half8 v0, v1;
#pragma unroll
    for (int j = 0; j < 8; j++) {
      v0[j] = (_Float16)(tile[kseg * 16 + j][c2] * 64.0f);
      v1[j] = (_Float16)(tile[kseg * 16 + 8 + j][c2] * 64.0f);
    }
    size_t n  = (size_t)g * 1024 + tc * 64 + c2;
    size_t kk = (size_t)s * 1024 + tr * 64 + kseg * 16;
    *(half8*)(Bhi + n * 2048 + kk) = v0;
    *(half8*)(Bhi + n * 2048 + kk + 8) = v1;
  } else {
    int n = (blk - 11264) * 256 + t;
    b_all[n] = bs.p[n >> 10][n & 1023];
  }
}

// ---------------------------------------------------------------------------
// GEMM: A[4096,2048] @ Bt[6144,2048]^T / 64 + bias -> pre16 (fp16, row-major).
// R9 config verbatim (measured 109-112us): triple-buffer ring BK=64,
// 1 barrier/tile, ks-split MFMA clusters, 3-bit XOR slot swizzle, grid 768 =
// 3 exact dispatch rounds at 1 block/CU.

#define LGKM0 asm volatile("s_waitcnt lgkmcnt(0)" ::: "memory")

__device__ __forceinline__ void wg_barrier() {
  __builtin_amdgcn_s_barrier();
  asm volatile("" ::: "memory");
}

__global__ __launch_bounds__(512, 2) void gemm_ring(
    const _Float16* __restrict__ Ah, const _Float16* __restrict__ Bh,
    const float* __restrict__ b_all, _Float16* __restrict__ pre16) {
  // 3 bufs x 24576 halfs (A 8192 + B 16384) = 144 KB. Epilogue reuses 66 KB.
  __shared__ __attribute__((aligned(16))) _Float16 lds[73728];

  // Bijective XCD swizzle: 768 blocks = 8 XCDs x 96; B-panel major chunks.
  const int bid = blockIdx.x;
  const int swz = (bid & 7) * 96 + (bid >> 3);
  const int nTile = swz / 32;   // 0..23
  const int mTile = swz % 32;   // 0..31

  const int t = threadIdx.x;
  const int lane = t & 63;
  const int wave = t >> 6;
  const int wm = wave >> 2, wn = wave & 3;       // 2 x 4 waves; per-wave 64x64
  const int kgrp = lane >> 4, frow = lane & 15;

  const _Float16* Abase = Ah + (size_t)mTile * 128 * 2048;
  const _Float16* Bbase = Bh + (size_t)nTile * 256 * 2048;

  f32x4 acc[4][4] = {};

  auto stage_tile = [&](int kt, int base) {
#pragma unroll
    for (int q = 0; q < 2; q++) {
      int s = q * 512 + t;
      int r = s >> 3, k8 = s & 7;
      int xs = k8 ^ (r & 7);
      async16(Abase + (size_t)r * 2048 + kt * 64 + xs * 8, lds + base + s * 8);
    }
#pragma unroll
    for (int q = 0; q < 4; q++) {
      int s = q * 512 + t;
      int r = s >> 3, k8 = s & 7;
      int xs = k8 ^ (r & 7);
      async16(Bbase + (size_t)r * 2048 + kt * 64 + xs * 8,
              lds + base + 8192 + s * 8);
    }
  };

  int cur = 0, nxt = 24576, nn = 49152;

  stage_tile(0, cur);
  stage_tile(1, nxt);
  asm volatile("s_waitcnt vmcnt(6)" ::: "memory");
  wg_barrier();

  for (int T = 0; T < 32; T++) {
    const _Float16* A_ = lds + cur;
    const _Float16* B_ = lds + cur + 8192;
    half8 af[4][2], bf[4][2];
#pragma unroll
    for (int mi = 0; mi < 4; mi++) {
      int r = wm * 64 + mi * 16 + frow;
#pragma unroll
      for (int ks = 0; ks < 2; ks++)
        af[mi][ks] = *(const half8*)(A_ + r * 64 +
                                     (((ks * 4 + kgrp) ^ (r & 7)) * 8));
    }
#pragma unroll
    for (int nj = 0; nj < 4; nj++) {
      int r = wn * 64 + nj * 16 + frow;
#pragma unroll
      for (int ks = 0; ks < 2; ks++)
        bf[nj][ks] = *(const half8*)(B_ + r * 64 +
                                     (((ks * 4 + kgrp) ^ (r & 7)) * 8));
    }
    if (T + 2 < 32) stage_tile(T + 2, nn);

    __builtin_amdgcn_s_setprio(1);
#pragma unroll
    for (int mi = 0; mi < 4; mi++)
#pragma unroll
      for (int nj = 0; nj < 4; nj++)
        acc[mi][nj] = __builtin_amdgcn_mfma_f32_16x16x32_f16(
            af[mi][0], bf[nj][0], acc[mi][nj], 0, 0, 0);
    __builtin_amdgcn_s_setprio(0);

    LGKM0;
    if (T < 30) {
      asm volatile("s_waitcnt vmcnt(6)" ::: "memory");
      wg_barrier();
    } else if (T == 30) {
      asm volatile("s_waitcnt vmcnt(0)" ::: "memory");
      wg_barrier();
    }

    __builtin_amdgcn_s_setprio(1);
#pragma unroll
    for (int mi = 0; mi < 4; mi++)
#pragma unroll
      for (int nj = 0; nj < 4; nj++)
        acc[mi][nj] = __builtin_amdgcn_mfma_f32_16x16x32_f16(
            af[mi][1], bf[nj][1], acc[mi][nj], 0, 0, 0);
    __builtin_amdgcn_s_setprio(0);

    int tmp = cur; cur = nxt; nxt = nn; nn = tmp;
  }

  __syncthreads();
  const float inv64 = 1.0f / 64.0f;
  const int cb = nTile * 256;
  float bias[4];
#pragma unroll
  for (int nj = 0; nj < 4; nj++)
    bias[nj] = b_all[cb + wn * 64 + nj * 16 + frow];
#pragma unroll
  for (int mi = 0; mi < 4; mi++) {
#pragma unroll
    for (int nj = 0; nj < 4; nj++) {
      int row = wm * 64 + mi * 16 + kgrp * 4;
      int col = wn * 64 + nj * 16 + frow;
#pragma unroll
      for (int j = 0; j < 4; j++)
        lds[(row + j) * 264 + col] =
            (_Float16)(acc[mi][nj][j] * inv64 + bias[nj]);
    }
  }
  __syncthreads();
#pragma unroll
  for (int rr = 0; rr < 8; rr++) {
    int L = rr * 4096 + t * 8;
    int row = L >> 8, col = L & 255;
    half8 v = *(const half8*)(lds + row * 264 + col);
    *(half8*)(pre16 + (size_t)(mTile * 128 + row) * 6144 + cb + col) = v;
  }
}

// ---------------------------------------------------------------------------
// Row softmax over zft/zit (fp16 in pre16, cols 4096..6143), p written back in
// place (fp16) + per-chunk (8-row) column sums into transposed part4.
// R12-tail config: 2 rows/wave, 1024 blocks.
__global__ void softmax_partials(_Float16* __restrict__ pre16, f32x4* __restrict__ part4) {
  __shared__ float wsum[4][1024];
  int m = blockIdx.x >> 9;           // 0: zft, 1: zit
  int ch = blockIdx.x & 511;         // chunk of 8 rows
  int t = threadIdx.x;
  int wave = t >> 6, lane = t & 63;
  f32x4 colacc[4] = {};
  for (int rr = 0; rr < 2; rr++) {
    int b = ch * 8 + wave * 2 + rr;
    _Float16* row = pre16 + (size_t)b * 6144 + (4 + m) * 1024;
    f32x4 v[4];
    float mx = -3.4e38f;
#pragma unroll
    for (int j = 0; j < 4; j++) {
      half4v h = *(const half4v*)(row + lane * 4 + 256 * j);
      v[j] = f32x4{ (float)h[0], (float)h[1], (float)h[2], (float)h[3] };
      mx = fmaxf(mx, fmaxf(fmaxf(v[j][0], v[j][1]), fmaxf(v[j][2], v[j][3])));
    }
#pragma unroll
    for (int off = 32; off > 0; off >>= 1) mx = fmaxf(mx, __shfl_xor(mx, off, 64));
    float sum = 0.f;
#pragma unroll
    for (int j = 0; j < 4; j++)
#pragma unroll
      for (int q = 0; q < 4; q++) { v[j][q] = __expf(v[j][q] - mx); sum += v[j][q]; }
#pragma unroll
    for (int off = 32; off > 0; off >>= 1) sum += __shfl_xor(sum, off, 64);
    float inv = 1.f / sum;
#pragma unroll
    for (int j = 0; j < 4; j++) {
      v[j] *= inv;
      half4v h = { (_Float16)v[j][0], (_Float16)v[j][1], (_Float16)v[j][2], (_Float16)v[j][3] };
      *(half4v*)(row + lane * 4 + 256 * j) = h;
      colacc[j] += v[j];
    }
  }
#pragma unroll
  for (int j = 0; j < 4; j++)
    *(f32x4*)(&wsum[wave][lane * 4 + 256 * j]) = colacc[j];
  __syncthreads();
  f32x4 s = *(const f32x4*)(&wsum[0][t * 4]);
  s += *(const f32x4*)(&wsum[1][t * 4]);
  s += *(const f32x4*)(&wsum[2][t * 4]);
  s += *(const f32x4*)(&wsum[3][t * 4]);
  part4[((size_t)m * 256 + t) * 512 + ch] = s;    // transposed: [m][c4][ch]
}

// Exclusive scan over 512 chunks per (m, c4-group): one wave per group,
// fully coalesced (contiguous 8 KB per wave in the transposed layout).
__global__ void scan_partials(const f32x4* __restrict__ part4, f32x4* __restrict__ off4) {
  int gidx = blockIdx.x * 4 + (threadIdx.x >> 6);   // 0..511 (m*256 + c4)
  int lane = threadIdx.x & 63;
  size_t base = (size_t)gidx * 512;
  f32x4 v[8];
  f32x4 s = {};
#pragma unroll
  for (int j = 0; j < 8; j++) {
    v[j] = part4[base + lane * 8 + j];
    s += v[j];
  }
  f32x4 incl = s;
#pragma unroll
  for (int off = 1; off < 64; off <<= 1) {
    f32x4 o;
#pragma unroll
    for (int q = 0; q < 4; q++) o[q] = __shfl_up(incl[q], off, 64);
    if (lane >= off) incl += o;
  }
  f32x4 run = incl - s;                            // exclusive prefix
#pragma unroll
  for (int j = 0; j < 8; j++) {
    off4[base + lane * 8 + j] = run;
    run += v[j];
  }
}

// Final: gates + cumsum + cell/hidden. 8-row chunks, 512 blocks.
// Fast transcendentals (R11): sigmoid via v_rcp_f32, tanh via (e-1)*rcp(e+1).
__device__ __forceinline__ float fast_sigmoid(float x) {
  return __builtin_amdgcn_rcpf(1.f + __expf(-x));
}
__device__ __forceinline__ float fast_tanh(float x) {
  float xc = fminf(fmaxf(x, -15.f), 15.f);
  float e = __expf(2.f * xc);
  return (e - 1.f) * __builtin_amdgcn_rcpf(e + 1.f);
}

__global__ void onlstm_final(const _Float16* __restrict__ pre16,
                             const float* __restrict__ cprev, const f32x4* __restrict__ off4,
                             float* __restrict__ out) {
  int ch = blockIdx.x;              // 0..511
  int c4 = threadIdx.x;
  int c = c4 * 4;
  f32x4 runf = off4[(size_t)c4 * 512 + ch];
  f32x4 runi = off4[(size_t)(256 + c4) * 512 + ch];
  for (int r = 0; r < 8; r++) {
    int b = ch * 8 + r;
    const _Float16* row = pre16 + (size_t)b * 6144;
    half4v zf = *(const half4v*)(row + c);
    half4v zi = *(const half4v*)(row + 1024 + c);
    half4v zo = *(const half4v*)(row + 2048 + c);
    half4v zc = *(const half4v*)(row + 3072 + c);
    half4v pf = *(const half4v*)(row + 4096 + c);
    half4v pi = *(const half4v*)(row + 5120 + c);
    f32x4 cp = *(const f32x4*)(cprev + (size_t)b * 1024 + c);
    f32x4 hid, cel;
#pragma unroll
    for (int q = 0; q < 4; q++) {
      runf[q] += (float)pf[q];
      runi[q] += (float)pi[q];
      float ft = runf[q], it = 1.f - runi[q];
      float f  = fast_sigmoid((float)zf[q]);
      float ii = fast_sigmoid((float)zi[q]);
      float o  = fast_sigmoid((float)zo[q]);
      float chat = fast_tanh((float)zc[q]);
      float omega = ft * it;
      float fhat = f * omega + (ft - omega);
      float ihat = ii * omega + (it - omega);
      float cell = fhat * cp[q] + ihat * chat;
      hid[q] = o * fast_tanh(cell);
      cel[q] = cell;
    }
    *(f32x4*)(out + (size_t)b * 1024 + c) = hid;
    *(f32x4*)(out + (size_t)4194304 + (size_t)b * 1024 + c) = cel;   // 4096*1024
  }
}

// ---------------------------------------------------------------------------
extern "C" void kernel_launch(void* const* d_in, const int* in_sizes, int n_in,
                              void* d_out, int out_size, void* d_ws, size_t ws_size,
                              hipStream_t stream) {
  const float* X = (const float*)d_in[0];
  const float* H = (const float*)d_in[1];
  const float* C = (const float*)d_in[2];

  char* ws = (char*)d_ws;
  _Float16* pre16 = (_Float16*)(ws);                      // 48 MB [4096][6144]
  _Float16* Ahi   = (_Float16*)(ws + 50331648);           // 16 MB (dead after gemm)
  _Float16* Bhi   = (_Float16*)(ws + 67108864);           // 24 MB (dead after gemm)
  float*    b_all = (float*)(ws + 92274688);              // 24 KB
  // part4/off4 (4 MB each) overlay the dead Ahi region [50331648, 67108864):
  // gemm completes before softmax launches (stream-ordered), no aliasing.
  f32x4*    part4 = (f32x4*)(ws + 50331648);              //  4 MB [2][256][512]
  f32x4*    off4  = (f32x4*)(ws + 54525952);              //  4 MB

  Ptrs12 w;
  for (int g = 0; g < 6; g++) {
    w.p[2 * g]     = (const float*)d_in[3 + 3 * g];   // Wg
    w.p[2 * g + 1] = (const float*)d_in[4 + 3 * g];   // Ug
  }
  Ptrs6 bs;
  for (int g = 0; g < 6; g++) bs.p[g] = (const float*)d_in[5 + 3 * g];

  prep<<<11288, 256, 0, stream>>>(X, H, w, bs, Ahi, Bhi, b_all);
  gemm_ring<<<768, 512, 0, stream>>>(Ahi, Bhi, b_all, pre16);
  softmax_partials<<<1024, 256, 0, stream>>>(pre16, part4);
  scan_partials<<<128, 256, 0, stream>>>(part4, off4);
  onlstm_final<<<512, 256, 0, stream>>>(pre16, C, off4, (float*)d_out);
}